// Round 2
// baseline (3772.747 us; speedup 1.0000x reference)
//
#include <hip/hip_runtime.h>
#include <hip/hip_bf16.h>
#include <stdint.h>

#define XS 128
#define YS 128
#define ZS 8
#define NQ (XS*YS*ZS)        // 131072 queries / voxels
#define CDIM 128
#define NH 8
#define HD 16
#define DH 192
#define DW 640
#define NPIX (DH*DW)         // 122880
#define NVPIX 10080          // 7680 + 1920 + 480
#define QB 4                 // queries per block in main kernel

// ---------------- inverse of K (3x3) and E (4x4), fp64, one thread ----------------
__global__ void inv_kernel(const float* __restrict__ K,
                           const float* __restrict__ E,
                           double* __restrict__ inv_out){
    if (threadIdx.x != 0 || blockIdx.x != 0) return;
    double k[3][3], e[4][4];
    for (int i=0;i<9;i++)  k[i/3][i%3] = (double)K[i];
    for (int i=0;i<16;i++) e[i/4][i%4] = (double)E[i];
    double det = k[0][0]*(k[1][1]*k[2][2]-k[1][2]*k[2][1])
               - k[0][1]*(k[1][0]*k[2][2]-k[1][2]*k[2][0])
               + k[0][2]*(k[1][0]*k[2][1]-k[1][1]*k[2][0]);
    double id = 1.0/det;
    double inv[3][3];
    inv[0][0]=(k[1][1]*k[2][2]-k[1][2]*k[2][1])*id;
    inv[0][1]=(k[0][2]*k[2][1]-k[0][1]*k[2][2])*id;
    inv[0][2]=(k[0][1]*k[1][2]-k[0][2]*k[1][1])*id;
    inv[1][0]=(k[1][2]*k[2][0]-k[1][0]*k[2][2])*id;
    inv[1][1]=(k[0][0]*k[2][2]-k[0][2]*k[2][0])*id;
    inv[1][2]=(k[0][2]*k[1][0]-k[0][0]*k[1][2])*id;
    inv[2][0]=(k[1][0]*k[2][1]-k[1][1]*k[2][0])*id;
    inv[2][1]=(k[0][1]*k[2][0]-k[0][0]*k[2][1])*id;
    inv[2][2]=(k[0][0]*k[1][1]-k[0][1]*k[1][0])*id;
    for (int i=0;i<9;i++) inv_out[i] = inv[i/3][i%3];
    // 4x4 Gauss-Jordan with partial pivoting
    double a[4][8];
    for (int i=0;i<4;i++){ for(int j=0;j<4;j++){ a[i][j]=e[i][j]; a[i][4+j]=(i==j)?1.0:0.0; } }
    for (int c=0;c<4;c++){
        int piv=c; double best=fabs(a[c][c]);
        for (int r=c+1;r<4;r++){ double v=fabs(a[r][c]); if (v>best){best=v;piv=r;} }
        if (piv!=c){ for (int j=0;j<8;j++){ double tmp=a[c][j]; a[c][j]=a[piv][j]; a[piv][j]=tmp; } }
        double pv = 1.0/a[c][c];
        for (int j=0;j<8;j++) a[c][j]*=pv;
        for (int r=0;r<4;r++){
            if (r==c) continue;
            double f=a[r][c];
            for(int j=0;j<8;j++) a[r][j]-=f*a[c][j];
        }
    }
    for (int i=0;i<16;i++) inv_out[9+i] = a[i/4][4 + (i%4)];
}

// ---------------- pix2vox + voxel mask (fp64 chain: trunc boundaries) ----------------
__global__ void mask_kernel(const float* __restrict__ depth,
                            const double* __restrict__ invm,
                            const float* __restrict__ vorigin,
                            unsigned char* __restrict__ mask){
    int tid = blockIdx.x*blockDim.x + threadIdx.x;
    if (tid >= NPIX) return;
    int gx = tid % DW, gy = tid / DW;
    double d  = (double)depth[tid];
    double X0 = (double)gx * d, X1 = (double)gy * d, X2 = d;
    double c0 = invm[0]*X0 + invm[1]*X1 + invm[2]*X2;
    double c1 = invm[3]*X0 + invm[4]*X1 + invm[5]*X2;
    double c2 = invm[6]*X0 + invm[7]*X1 + invm[8]*X2;
    const double* iE = invm + 9;
    double w0 = iE[0]*c0 + iE[1]*c1 + iE[2]*c2  + iE[3];
    double w1 = iE[4]*c0 + iE[5]*c1 + iE[6]*c2  + iE[7];
    double w2 = iE[8]*c0 + iE[9]*c1 + iE[10]*c2 + iE[11];
    double o0 = (double)vorigin[0];
    double o1 = (double)vorigin[1];
    double o2 = (double)vorigin[2];
    double v0 = (w0-o0)/0.4 - 0.5;
    double v1 = (w1-o1)/0.4 - 0.5;
    double v2 = ((w2-o2)/0.4 - 0.5) / 2.0;   // DOWNSAMPLE_Z
    int xi = (int)v0, yi = (int)v1, zi = (int)v2;   // trunc toward zero == jnp.trunc
    if (xi>=0 && xi<XS && yi>=0 && yi<YS && zi>=0 && zi<ZS)
        mask[(xi*YS + yi)*ZS + zi] = 1;
}

// ---------------- value = flat @ Wv.T + bv  (10080 x 128) ----------------
__global__ __launch_bounds__(128)
void value_kernel(const float* __restrict__ f0,
                  const float* __restrict__ f1,
                  const float* __restrict__ f2,
                  const float* __restrict__ Wv,
                  const float* __restrict__ bv,
                  float* __restrict__ value){
    int p = blockIdx.x, t = threadIdx.x;
    __shared__ float fl[CDIM];
    const float* src; int hw, lp;
    if (p < 7680)      { src=f0; hw=7680; lp=p; }
    else if (p < 9600) { src=f1; hw=1920; lp=p-7680; }
    else               { src=f2; hw=480;  lp=p-9600; }
    fl[t] = src[t*hw + lp];   // flat[p, c] = feat[c, p]
    __syncthreads();
    const float4* wrow = (const float4*)(Wv + t*CDIM);
    float acc = bv[t];
    #pragma unroll
    for (int kk=0; kk<32; ++kk){
        float4 w = wrow[kk];
        acc += fl[kk*4+0]*w.x + fl[kk*4+1]*w.y + fl[kk*4+2]*w.z + fl[kk*4+3]*w.w;
    }
    value[p*CDIM + t] = acc;
}

// ---------------- fused deformable attention + Wout + LN + mask-select ----------------
// One block = QB=4 consecutive queries; 128 threads. Writes transposed output
// directly: thread t owns channel c=t, stores float4 at d_out[t*NQ + n0].
__global__ __launch_bounds__(128)
void main_kernel(const float* __restrict__ q_in,
                 const float* __restrict__ refpix,
                 const float* __restrict__ Woff,
                 const float* __restrict__ boff,
                 const float* __restrict__ Wattw,
                 const float* __restrict__ battw,
                 const float* __restrict__ Wout,
                 const float* __restrict__ bout,
                 const float* __restrict__ lng,
                 const float* __restrict__ lnb,
                 const float* __restrict__ value,
                 const unsigned char* __restrict__ mask,
                 float* __restrict__ dout){
    const int n0 = blockIdx.x * QB, t = threadIdx.x;
    __shared__ float q_s[QB][CDIM];
    __shared__ float off_s[QB][192];
    __shared__ float aw_s[QB][96];
    __shared__ float out_s[QB][CDIM];
    __shared__ float wred[2][2][QB];   // [sum/var][wave][qi]

    #pragma unroll
    for (int qi=0; qi<QB; ++qi)
        q_s[qi][t] = q_in[(n0+qi)*CDIM + t];
    __syncthreads();

    // offsets (192) + attention logits (96): 288 rows x QB queries
    for (int j = t; j < 288; j += 128){
        const float* wrow; float acc[QB];
        if (j < 192){ wrow = Woff  + j*CDIM;       float b=boff[j];
                      for (int qi=0;qi<QB;qi++) acc[qi]=b; }
        else        { wrow = Wattw + (j-192)*CDIM; float b=battw[j-192];
                      for (int qi=0;qi<QB;qi++) acc[qi]=b; }
        const float4* w4 = (const float4*)wrow;
        #pragma unroll
        for (int kk=0; kk<32; ++kk){
            float4 w = w4[kk];
            #pragma unroll
            for (int qi=0; qi<QB; ++qi){
                acc[qi] += q_s[qi][kk*4+0]*w.x + q_s[qi][kk*4+1]*w.y
                         + q_s[qi][kk*4+2]*w.z + q_s[qi][kk*4+3]*w.w;
            }
        }
        if (j<192){ for (int qi=0;qi<QB;qi++) off_s[qi][j]     = acc[qi]; }
        else      { for (int qi=0;qi<QB;qi++) aw_s[qi][j-192]  = acc[qi]; }
    }
    __syncthreads();

    // softmax over L*P=12 per (query, head): 32 threads
    if (t < QB*NH){
        const int qi = t >> 3, h = t & 7;
        float m = -1e30f;
        #pragma unroll
        for (int i=0;i<12;i++) m = fmaxf(m, aw_s[qi][h*12+i]);
        float e[12]; float s = 0.f;
        #pragma unroll
        for (int i=0;i<12;i++){ e[i] = __expf(aw_s[qi][h*12+i]-m); s += e[i]; }
        float is = 1.f/s;
        #pragma unroll
        for (int i=0;i<12;i++) aw_s[qi][h*12+i] = e[i]*is;
    }
    __syncthreads();

    // bilinear sampling: thread = (head, channel-within-head)
    const int h = t >> 4, c = t & 15;
    float accv[QB] = {0.f,0.f,0.f,0.f};
    const int Wl[3]={160,80,40}, Hl[3]={48,24,12}, st[3]={0,7680,9600};
    #pragma unroll
    for (int l=0;l<3;l++){
        const float fw = (float)Wl[l], fh = (float)Hl[l];
        #pragma unroll
        for (int p=0;p<4;p++){
            #pragma unroll
            for (int qi=0; qi<QB; ++qi){
                const int ob = ((h*3+l)*4+p)*2;
                float locx = refpix[(n0+qi)*2+0] + off_s[qi][ob]   / fw;
                float locy = refpix[(n0+qi)*2+1] + off_s[qi][ob+1] / fh;
                float x = locx*fw - 0.5f;
                float y = locy*fh - 0.5f;
                float x0f = floorf(x), y0f = floorf(y);
                float lx = x - x0f, ly = y - y0f;
                int x0 = (int)x0f, y0 = (int)y0f;
                float s = 0.f;
                #pragma unroll
                for (int dy=0;dy<2;dy++){
                    #pragma unroll
                    for (int dx=0;dx<2;dx++){
                        int xi = x0+dx, yi = y0+dy;
                        if (xi>=0 && xi<Wl[l] && yi>=0 && yi<Hl[l]){
                            float wgt = (dx ? lx : 1.f-lx) * (dy ? ly : 1.f-ly);
                            s += value[(st[l] + yi*Wl[l] + xi)*CDIM + h*HD + c] * wgt;
                        }
                    }
                }
                accv[qi] += aw_s[qi][h*12 + l*4 + p] * s;
            }
        }
    }
    #pragma unroll
    for (int qi=0;qi<QB;qi++) out_s[qi][t] = accv[qi];
    __syncthreads();

    // attn = out @ Wout.T + bout
    float acc[QB];
    { float b = bout[t]; for (int qi=0;qi<QB;qi++) acc[qi]=b; }
    const float4* w4 = (const float4*)(Wout + t*CDIM);
    #pragma unroll
    for (int kk=0;kk<32;kk++){
        float4 w = w4[kk];
        #pragma unroll
        for (int qi=0; qi<QB; ++qi){
            acc[qi] += out_s[qi][kk*4+0]*w.x + out_s[qi][kk*4+1]*w.y
                     + out_s[qi][kk*4+2]*w.z + out_s[qi][kk*4+3]*w.w;
        }
    }

    // residual + LayerNorm (wave-shuffle reductions) + mask select
    float hv[QB], sred[QB];
    #pragma unroll
    for (int qi=0;qi<QB;qi++){ hv[qi] = q_s[qi][t] + acc[qi]; sred[qi]=hv[qi]; }
    #pragma unroll
    for (int off=32; off>0; off>>=1)
        for (int qi=0;qi<QB;qi++) sred[qi] += __shfl_xor(sred[qi], off, 64);
    if ((t&63)==0){ for (int qi=0;qi<QB;qi++) wred[0][t>>6][qi]=sred[qi]; }
    __syncthreads();
    float mu[QB], dv[QB];
    #pragma unroll
    for (int qi=0;qi<QB;qi++){
        mu[qi] = (wred[0][0][qi]+wred[0][1][qi]) * (1.f/128.f);
        dv[qi] = hv[qi]-mu[qi];
        sred[qi] = dv[qi]*dv[qi];
    }
    #pragma unroll
    for (int off=32; off>0; off>>=1)
        for (int qi=0;qi<QB;qi++) sred[qi] += __shfl_xor(sred[qi], off, 64);
    if ((t&63)==0){ for (int qi=0;qi<QB;qi++) wred[1][t>>6][qi]=sred[qi]; }
    __syncthreads();

    float res[QB];
    const float g = lng[t], b = lnb[t];
    #pragma unroll
    for (int qi=0;qi<QB;qi++){
        float var = (wred[1][0][qi]+wred[1][1][qi]) * (1.f/128.f);
        float nv  = dv[qi] * __frsqrt_rn(var + 1e-5f) * g + b;
        res[qi] = mask[n0+qi] ? nv : q_s[qi][t];
    }
    float4 o; o.x=res[0]; o.y=res[1]; o.z=res[2]; o.w=res[3];
    *(float4*)(dout + (size_t)t*NQ + n0) = o;
}

extern "C" void kernel_launch(void* const* d_in, const int* in_sizes, int n_in,
                              void* d_out, int out_size, void* d_ws, size_t ws_size,
                              hipStream_t stream){
    const float* scene  = (const float*)d_in[0];
    const float* f0     = (const float*)d_in[1];
    const float* f1     = (const float*)d_in[2];
    const float* f2     = (const float*)d_in[3];
    const float* depth  = (const float*)d_in[4];
    const float* K      = (const float*)d_in[5];
    const float* E      = (const float*)d_in[6];
    const float* vorig  = (const float*)d_in[7];
    const float* refpix = (const float*)d_in[8];
    const float* Wv     = (const float*)d_in[9];
    const float* bv     = (const float*)d_in[10];
    const float* Woff   = (const float*)d_in[11];
    const float* boff   = (const float*)d_in[12];
    const float* Wattw  = (const float*)d_in[13];
    const float* battw  = (const float*)d_in[14];
    const float* Wout   = (const float*)d_in[15];
    const float* bout   = (const float*)d_in[16];
    const float* lng    = (const float*)d_in[17];
    const float* lnb    = (const float*)d_in[18];

    char* ws = (char*)d_ws;
    double*        invm  = (double*)(ws);                  // 25 doubles
    unsigned char* mask  = (unsigned char*)(ws + 512);     // 131072 B
    float*         value = (float*)(ws + 512 + 131072);    // 10080*128*4 = 5160960 B

    hipMemsetAsync(mask, 0, NQ, stream);
    inv_kernel<<<1, 64, 0, stream>>>(K, E, invm);
    mask_kernel<<<(NPIX+255)/256, 256, 0, stream>>>(depth, invm, vorig, mask);
    value_kernel<<<NVPIX, 128, 0, stream>>>(f0, f1, f2, Wv, bv, value);
    main_kernel<<<NQ/QB, 128, 0, stream>>>(scene, refpix, Woff, boff, Wattw, battw,
                                           Wout, bout, lng, lnb, value, mask,
                                           (float*)d_out);
}